// Round 5
// baseline (3686.488 us; speedup 1.0000x reference)
//
#include <hip/hip_runtime.h>
#include <hip/hip_bf16.h>

// HRMHead via bf16 MFMA. B=1024, T=512, F=128, H=64, HIGH_PERIOD=10.
// R5: 2 real rows/block (M=16 tile, 8x dup), 512 blocks -> 2 blocks/CU
//     (2 waves/SIMD for latency hiding), x prefetch distance 2,
//     split MFMA dep chains, double-buffered Ahh.

#define T_STEPS 512
#define F_IN 128

typedef __attribute__((ext_vector_type(8))) short s16x8;
typedef __attribute__((ext_vector_type(4))) float f32x4;

__device__ __forceinline__ float sigm(float v) { return 1.0f / (1.0f + __expf(-v)); }
__device__ __forceinline__ float tanh_fast(float v) { return 1.0f - 2.0f / (__expf(2.0f * v) + 1.0f); }
__device__ __forceinline__ short f2b(float f) {
    __hip_bfloat16 h = __float2bfloat16(f);
    union { __hip_bfloat16 h; short s; } u; u.h = h; return u.s;
}

// ws layout (shorts): lowGi [12][6][64][8] @0 ; lowGh [12][2][64][8] @36864 ;
// highGi [12][4][64][8] @49152 ; highGh [12][2][64][8] @73728 ; W1t fp32 [64][64] @86016
__global__ void prep_pack(const float* __restrict__ hWih, const float* __restrict__ hWhh,
                          const float* __restrict__ lWih, const float* __restrict__ lWhh,
                          const float* __restrict__ headW1,
                          short* __restrict__ wsS) {
    int i = blockIdx.x * blockDim.x + threadIdx.x;
    if (i < 36864) {
        int j = i & 7, l = (i >> 3) & 63, tile = i >> 9;
        int kt = tile % 6, nt = tile / 6;
        int n = nt * 16 + (l & 15), k = kt * 32 + (l >> 4) * 8 + j;
        wsS[i] = f2b(lWih[n * 192 + k]);
    } else if (i < 49152) {
        int fi = i - 36864;
        int j = fi & 7, l = (fi >> 3) & 63, tile = fi >> 9;
        int kt = tile & 1, nt = tile >> 1;
        int n = nt * 16 + (l & 15), k = kt * 32 + (l >> 4) * 8 + j;
        wsS[i] = f2b(lWhh[n * 64 + k]);
    } else if (i < 73728) {
        int fi = i - 49152;
        int j = fi & 7, l = (fi >> 3) & 63, tile = fi >> 9;
        int kt = tile & 3, nt = tile >> 2;
        int n = nt * 16 + (l & 15), k = kt * 32 + (l >> 4) * 8 + j;
        wsS[i] = f2b(hWih[n * 128 + k]);
    } else if (i < 86016) {
        int fi = i - 73728;
        int j = fi & 7, l = (fi >> 3) & 63, tile = fi >> 9;
        int kt = tile & 1, nt = tile >> 1;
        int n = nt * 16 + (l & 15), k = kt * 32 + (l >> 4) * 8 + j;
        wsS[i] = f2b(hWhh[n * 64 + k]);
    } else if (i < 86016 + 4096) {
        int fi = i - 86016;
        int jj = fi & 63, k = fi >> 6;
        float* W1t = (float*)(wsS + 86016);
        W1t[k * 64 + jj] = headW1[jj * 64 + k];
    }
}

__global__ __launch_bounds__(256, 2)
void hrm_mfma(const float* __restrict__ x,
              const float* __restrict__ high_bih, const float* __restrict__ high_bhh,
              const float* __restrict__ low_bih,  const float* __restrict__ low_bhh,
              const float* __restrict__ head_b1,  const float* __restrict__ head_W2,
              const float* __restrict__ head_b2,
              const short* __restrict__ wsS,
              float* __restrict__ out) {
    const int tid = threadIdx.x;
    const int w = tid >> 6, l = tid & 63;
    const int lo4 = l & 15, hi4 = l >> 4;
    const int j = w * 16 + lo4;   // this lane's hidden col in elementwise phase

    const s16x8* pLGi = (const s16x8*)wsS;
    const s16x8* pLGh = (const s16x8*)(wsS + 36864);
    const s16x8* pHGi = (const s16x8*)(wsS + 49152);
    const s16x8* pHGh = (const s16x8*)(wsS + 73728);
    const float* W1t  = (const float*)(wsS + 86016);

    __shared__ __align__(16) short Ahl[2][16 * 72];  // h_low bf16 A-frags, double-buffered
    __shared__ __align__(16) short Ahh[2][16 * 72];  // h_high bf16 A-frags, double-buffered
    __shared__ float hlf[16][68];

    for (int i = tid; i < 2 * 16 * 72; i += 256) ((short*)Ahl)[i] = 0;
    for (int i = tid; i < 2 * 16 * 72; i += 256) ((short*)Ahh)[i] = 0;

    float lbi[3], lbh[3], hbi[3], hbh[3];
    #pragma unroll
    for (int g = 0; g < 3; ++g) {
        lbi[g] = low_bih[g * 64 + j];  lbh[g] = low_bhh[g * 64 + j];
        hbi[g] = high_bih[g * 64 + j]; hbh[g] = high_bhh[g * 64 + j];
    }

    // low-cell weights resident in VGPRs (one-time load, L2-broadcast)
    s16x8 Bgi[3][6], Bgh[3][2];
    #pragma unroll
    for (int g = 0; g < 3; ++g) {
        #pragma unroll
        for (int kt = 0; kt < 6; ++kt) Bgi[g][kt] = pLGi[((g * 4 + w) * 6 + kt) * 64 + l];
        #pragma unroll
        for (int kt = 0; kt < 2; ++kt) Bgh[g][kt] = pLGh[((g * 4 + w) * 2 + kt) * 64 + l];
    }

    float hl[4] = {0.f, 0.f, 0.f, 0.f};
    float hh[4] = {0.f, 0.f, 0.f, 0.f};

    const int r0 = blockIdx.x * 2;
    // A-frag row (lo4) -> real row (lo4 & 1); lane reads 8 consecutive floats of x
    const float* xlane = x + ((size_t)(r0 + (lo4 & 1)) * T_STEPS) * F_IN + hi4 * 8;

    // x prefetch: distance 2, register double-buffer
    f32x4 xraw[2][4][2];
    #pragma unroll
    for (int kt = 0; kt < 4; ++kt) {
        xraw[0][kt][0] = *(const f32x4*)(xlane + kt * 32);
        xraw[0][kt][1] = *(const f32x4*)(xlane + kt * 32 + 4);
        xraw[1][kt][0] = *(const f32x4*)(xlane + F_IN + kt * 32);
        xraw[1][kt][1] = *(const f32x4*)(xlane + F_IN + kt * 32 + 4);
    }

    __syncthreads();

    int tmod = 0, hb = 0;
    for (int t = 0; t < T_STEPS; ++t) {
        const int cur = t & 1;
        // convert current x to bf16 A-frags
        s16x8 xf[4];
        #pragma unroll
        for (int kt = 0; kt < 4; ++kt) {
            union { s16x8 v; __hip_bfloat162 h2[4]; } u;
            u.h2[0] = __float22bfloat162_rn(make_float2(xraw[cur][kt][0].x, xraw[cur][kt][0].y));
            u.h2[1] = __float22bfloat162_rn(make_float2(xraw[cur][kt][0].z, xraw[cur][kt][0].w));
            u.h2[2] = __float22bfloat162_rn(make_float2(xraw[cur][kt][1].x, xraw[cur][kt][1].y));
            u.h2[3] = __float22bfloat162_rn(make_float2(xraw[cur][kt][1].z, xraw[cur][kt][1].w));
            xf[kt] = u.v;
        }
        // issue prefetch for t+2 into the buffer just consumed (2 steps to complete)
        if (t + 2 < T_STEPS) {
            #pragma unroll
            for (int kt = 0; kt < 4; ++kt) {
                xraw[cur][kt][0] = *(const f32x4*)(xlane + (size_t)(t + 2) * F_IN + kt * 32);
                xraw[cur][kt][1] = *(const f32x4*)(xlane + (size_t)(t + 2) * F_IN + kt * 32 + 4);
            }
        }

        const int rb = cur, wbf = cur ^ 1;

        if (tmod == 0) {
            // ---- high GRU cell (uses OLD h_high in Ahh[hb], x_t) ----
            s16x8 ah0 = *(const s16x8*)&Ahh[hb][lo4 * 72 + hi4 * 8];
            s16x8 ah1 = *(const s16x8*)&Ahh[hb][lo4 * 72 + 32 + hi4 * 8];
            f32x4 giA[3], giB[3], gh[3];
            #pragma unroll
            for (int g = 0; g < 3; ++g) {
                giA[g] = (f32x4){hbi[g], hbi[g], hbi[g], hbi[g]};
                giB[g] = (f32x4){0.f, 0.f, 0.f, 0.f};
                gh[g]  = (f32x4){hbh[g], hbh[g], hbh[g], hbh[g]};
            }
            #pragma unroll
            for (int g = 0; g < 3; ++g) {
                s16x8 b0 = pHGh[((g * 4 + w) * 2 + 0) * 64 + l];
                s16x8 b1 = pHGh[((g * 4 + w) * 2 + 1) * 64 + l];
                gh[g] = __builtin_amdgcn_mfma_f32_16x16x32_bf16(ah0, b0, gh[g], 0, 0, 0);
                gh[g] = __builtin_amdgcn_mfma_f32_16x16x32_bf16(ah1, b1, gh[g], 0, 0, 0);
            }
            #pragma unroll
            for (int g = 0; g < 3; ++g) {
                s16x8 b0 = pHGi[((g * 4 + w) * 4 + 0) * 64 + l];
                s16x8 b1 = pHGi[((g * 4 + w) * 4 + 1) * 64 + l];
                s16x8 b2 = pHGi[((g * 4 + w) * 4 + 2) * 64 + l];
                s16x8 b3 = pHGi[((g * 4 + w) * 4 + 3) * 64 + l];
                giA[g] = __builtin_amdgcn_mfma_f32_16x16x32_bf16(xf[0], b0, giA[g], 0, 0, 0);
                giB[g] = __builtin_amdgcn_mfma_f32_16x16x32_bf16(xf[2], b2, giB[g], 0, 0, 0);
                giA[g] = __builtin_amdgcn_mfma_f32_16x16x32_bf16(xf[1], b1, giA[g], 0, 0, 0);
                giB[g] = __builtin_amdgcn_mfma_f32_16x16x32_bf16(xf[3], b3, giB[g], 0, 0, 0);
            }
            #pragma unroll
            for (int q = 0; q < 4; ++q) {
                float gi0 = giA[0][q] + giB[0][q];
                float gi1 = giA[1][q] + giB[1][q];
                float gi2 = giA[2][q] + giB[2][q];
                float r = sigm(gi0 + gh[0][q]);
                float z = sigm(gi1 + gh[1][q]);
                float n = tanh_fast(gi2 + r * gh[2][q]);
                hh[q] = (1.0f - z) * n + z * hh[q];
            }
            // write NEW h_high into the other buffer (nobody reads it)
            #pragma unroll
            for (int q = 0; q < 4; ++q)
                Ahh[hb ^ 1][(hi4 * 4 + q) * 72 + j] = f2b(hh[q]);
            __syncthreads();   // new Ahh visible to all waves
            hb ^= 1;
        }
        if (++tmod == 10) tmod = 0;

        // ---- low GRU cell ----
        s16x8 al0 = *(const s16x8*)&Ahl[rb][lo4 * 72 + hi4 * 8];
        s16x8 al1 = *(const s16x8*)&Ahl[rb][lo4 * 72 + 32 + hi4 * 8];
        s16x8 ah0 = *(const s16x8*)&Ahh[hb][lo4 * 72 + hi4 * 8];
        s16x8 ah1 = *(const s16x8*)&Ahh[hb][lo4 * 72 + 32 + hi4 * 8];

        f32x4 giA[3], giB[3], gh[3];
        #pragma unroll
        for (int g = 0; g < 3; ++g) {
            giA[g] = (f32x4){lbi[g], lbi[g], lbi[g], lbi[g]};
            giB[g] = (f32x4){0.f, 0.f, 0.f, 0.f};
            gh[g]  = (f32x4){lbh[g], lbh[g], lbh[g], lbh[g]};
        }
        #pragma unroll
        for (int g = 0; g < 3; ++g) {
            gh[g] = __builtin_amdgcn_mfma_f32_16x16x32_bf16(al0, Bgh[g][0], gh[g], 0, 0, 0);
            gh[g] = __builtin_amdgcn_mfma_f32_16x16x32_bf16(al1, Bgh[g][1], gh[g], 0, 0, 0);
        }
        #pragma unroll
        for (int g = 0; g < 3; ++g) {
            giA[g] = __builtin_amdgcn_mfma_f32_16x16x32_bf16(xf[0], Bgi[g][0], giA[g], 0, 0, 0);
            giB[g] = __builtin_amdgcn_mfma_f32_16x16x32_bf16(xf[2], Bgi[g][2], giB[g], 0, 0, 0);
            giA[g] = __builtin_amdgcn_mfma_f32_16x16x32_bf16(xf[1], Bgi[g][1], giA[g], 0, 0, 0);
            giB[g] = __builtin_amdgcn_mfma_f32_16x16x32_bf16(xf[3], Bgi[g][3], giB[g], 0, 0, 0);
            giA[g] = __builtin_amdgcn_mfma_f32_16x16x32_bf16(ah0, Bgi[g][4], giA[g], 0, 0, 0);
            giB[g] = __builtin_amdgcn_mfma_f32_16x16x32_bf16(ah1, Bgi[g][5], giB[g], 0, 0, 0);
        }

        #pragma unroll
        for (int q = 0; q < 4; ++q) {
            float gi0 = giA[0][q] + giB[0][q];
            float gi1 = giA[1][q] + giB[1][q];
            float gi2 = giA[2][q] + giB[2][q];
            float r = sigm(gi0 + gh[0][q]);
            float z = sigm(gi1 + gh[1][q]);
            float n = tanh_fast(gi2 + r * gh[2][q]);
            hl[q] = (1.0f - z) * n + z * hl[q];
        }
        #pragma unroll
        for (int q = 0; q < 4; ++q)
            Ahl[wbf][(hi4 * 4 + q) * 72 + j] = f2b(hl[q]);
        __syncthreads();   // Ahl[wbf] visible for next step
    }

    // ---- head ----
    #pragma unroll
    for (int q = 0; q < 4; ++q) hlf[hi4 * 4 + q][j] = hl[q];
    __syncthreads();

    // waves 0,1 handle real rows 0,1 (hlf rows 0,1); lane l = hidden unit
    if (w < 2) {
        float hd = head_b1[l];
        for (int k = 0; k < 64; ++k)
            hd = fmaf(hlf[w][k], W1t[k * 64 + l], hd);
        hd = fmaxf(hd, 0.0f);
        float v = hd * head_W2[l];
        #pragma unroll
        for (int off = 32; off > 0; off >>= 1) v += __shfl_down(v, off);
        if (l == 0) out[r0 + w] = sigm(v + head_b2[0]);
    }
}

extern "C" void kernel_launch(void* const* d_in, const int* in_sizes, int n_in,
                              void* d_out, int out_size, void* d_ws, size_t ws_size,
                              hipStream_t stream) {
    (void)in_sizes; (void)n_in; (void)out_size; (void)ws_size;
    const float* x        = (const float*)d_in[0];
    const float* high_Wih = (const float*)d_in[1];
    const float* high_Whh = (const float*)d_in[2];
    const float* high_bih = (const float*)d_in[3];
    const float* high_bhh = (const float*)d_in[4];
    const float* low_Wih  = (const float*)d_in[5];
    const float* low_Whh  = (const float*)d_in[6];
    const float* low_bih  = (const float*)d_in[7];
    const float* low_bhh  = (const float*)d_in[8];
    const float* head_W1  = (const float*)d_in[9];
    const float* head_b1  = (const float*)d_in[10];
    const float* head_W2  = (const float*)d_in[11];
    const float* head_b2  = (const float*)d_in[12];
    short* wsS = (short*)d_ws;
    float* out = (float*)d_out;

    prep_pack<<<352, 256, 0, stream>>>(high_Wih, high_Whh, low_Wih, low_Whh, head_W1, wsS);
    hrm_mfma<<<512, 256, 0, stream>>>(x, high_bih, high_bhh, low_bih, low_bhh,
                                      head_b1, head_W2, head_b2, wsS, out);
}